// Round 5
// baseline (288.218 us; speedup 1.0000x reference)
//
#include <hip/hip_runtime.h>

// sim[x] = (1/9) * sum_c unit[c,x]*box3x3(unit)[c,x],  unit = p * inv,  inv = 1/||p||_c
// out[b, c&1, h, w, c>>1] = p[b,c,h,w] * sim[b,h,w]
//
// Kernel A: inv[256][32][32] (d_ws) via coalesced streaming (the one cold HBM read).
// Kernel B: per (b, 4-row strip): stage raw p in XOR-swizzled LDS slab (2 chunks of
// 64 ch), wave-uniform row-blocked stencil with inline inv (padded invLp zeroes all
// OOB), shfl+LDS channel reduce, output transpose via T[128][36] (conflict-free,
// full-line coalesced writes).

#define NTHR_A 256
#define NTHR_B 512

__global__ __launch_bounds__(NTHR_A) void bcim_norm(const float* __restrict__ p,
                                                    float* __restrict__ inv) {
    __shared__ float scratch[8 * 4 * 32];
    const int tid = threadIdx.x;
    const int b  = blockIdx.x >> 3;
    const int r0 = (blockIdx.x & 7) << 2;
    const float* __restrict__ pb = p + (size_t)b * 131072;
    const int csub = tid >> 5, r = (tid >> 3) & 3, wq = tid & 7;
    float4 n = make_float4(0.f, 0.f, 0.f, 0.f);
    #pragma unroll
    for (int i = 0; i < 16; ++i) {
        const int c = csub * 16 + i;
        const float4 v = *(const float4*)(pb + c * 1024 + (r0 + r) * 32 + wq * 4);
        n.x = fmaf(v.x, v.x, n.x); n.y = fmaf(v.y, v.y, n.y);
        n.z = fmaf(v.z, v.z, n.z); n.w = fmaf(v.w, v.w, n.w);
    }
    *(float4*)&scratch[csub * 128 + r * 32 + wq * 4] = n;
    __syncthreads();
    if (tid < 128) {
        const int rr = tid >> 5, w = tid & 31;
        float s = 0.f;
        #pragma unroll
        for (int k = 0; k < 8; ++k) s += scratch[k * 128 + rr * 32 + w];
        inv[b * 1024 + (r0 + rr) * 32 + w] = (s > 0.f) ? (1.0f / sqrtf(s)) : 0.f;
    }
}

__global__ __launch_bounds__(NTHR_B, 4) void bcim_main(const float* __restrict__ p,
                                                       const float* __restrict__ inv,
                                                       float* __restrict__ out) {
    __shared__ float slab[12288];   // [c2 0..63][r 0..5][quad 0..7]*4, quad swz: wq^(c2&7)
    __shared__ float Tarea[4608];   // phase3 T[c][9 quads]*4; also R[32][8][16] (4096 f)
    __shared__ float invLp[6 * 34]; // padded: col0 and col33 = 0
    __shared__ float simv[128];

    const int tid = threadIdx.x;
    const int b  = blockIdx.x >> 3;
    const int r0 = (blockIdx.x & 7) << 2;
    const float* __restrict__ pb = p + (size_t)b * 131072;

    const int wv   = tid >> 6;      // 0..7 (wave id)
    const int rS   = wv >> 1;       // 0..3
    const int half = wv & 1;
    const int cS   = tid & 63;
    const int swz  = cS & 7;
    const int qb   = half ? 3 : 0;

    // ---- invLp (rows r0-1..r0+4; OOB rows & pad cols = 0) ----
    if (tid < 192) {
        const int j = tid >> 5, w = tid & 31;
        const int rg = r0 - 1 + j;
        float v = 0.f;
        if ((unsigned)rg < 32u) v = inv[b * 1024 + rg * 32 + w];
        invLp[j * 34 + 1 + w] = v;
    } else if (tid < 204) {
        const int t2 = tid - 192;
        invLp[(t2 >> 1) * 34 + ((t2 & 1) ? 33 : 0)] = 0.f;
    }

    // ---- chunk-0 prefetch (global -> regs), address precompute ----
    float4 st[6];
    int gOff[6], lOff[6];
    #pragma unroll
    for (int i = 0; i < 6; ++i) {
        const int flat = i * 512 + tid;
        const int c = flat / 48;
        const int rem = flat - c * 48;
        const int r = rem >> 3, wq = rem & 7;
        const int rg = min(max(r0 - 1 + r, 0), 31);   // clamp; inv=0 nullifies OOB rows
        gOff[i] = c * 1024 + rg * 32 + wq * 4;
        lOff[i] = (c * 48 + r * 8 + (wq ^ (c & 7))) * 4;
        st[i] = *(const float4*)(pb + gOff[i]);
    }
    __syncthreads();

    float acc[16];
    #pragma unroll
    for (int i = 0; i < 16; ++i) acc[i] = 0.f;

    const float* iT = &invLp[rS * 34 + half * 16];
    const float* iM = iT + 34;
    const float* iB = iM + 34;

    #pragma unroll
    for (int chunk = 0; chunk < 2; ++chunk) {
        #pragma unroll
        for (int i = 0; i < 6; ++i) *(float4*)&slab[lOff[i]] = st[i];
        __syncthreads();
        if (chunk == 0) {
            #pragma unroll
            for (int i = 0; i < 6; ++i) st[i] = *(const float4*)(pb + 65536 + gOff[i]);
        }
        float vs[18];
        float X[20];
        // row A (slab row rS), weight iT
        #pragma unroll
        for (int jj = 0; jj < 5; ++jj)
            *(float4*)&X[jj * 4] = *(const float4*)&slab[(cS * 48 + rS * 8 + ((qb + jj) ^ swz)) * 4];
        #pragma unroll
        for (int m = 0; m < 18; ++m) {
            const float xv = half ? ((m == 17) ? 0.f : X[m + 3])
                                  : ((m == 0)  ? 0.f : X[m - 1]);
            vs[m] = xv * iT[m];
        }
        // row E (slab row rS+2), weight iB
        #pragma unroll
        for (int jj = 0; jj < 5; ++jj)
            *(float4*)&X[jj * 4] = *(const float4*)&slab[(cS * 48 + (rS + 2) * 8 + ((qb + jj) ^ swz)) * 4];
        #pragma unroll
        for (int m = 0; m < 18; ++m) {
            const float xv = half ? ((m == 17) ? 0.f : X[m + 3])
                                  : ((m == 0)  ? 0.f : X[m - 1]);
            vs[m] = fmaf(xv, iB[m], vs[m]);
        }
        // row D (slab row rS+1), weight iM; X kept for the acc pass
        #pragma unroll
        for (int jj = 0; jj < 5; ++jj)
            *(float4*)&X[jj * 4] = *(const float4*)&slab[(cS * 48 + (rS + 1) * 8 + ((qb + jj) ^ swz)) * 4];
        #pragma unroll
        for (int m = 0; m < 18; ++m) {
            const float xv = half ? ((m == 17) ? 0.f : X[m + 3])
                                  : ((m == 0)  ? 0.f : X[m - 1]);
            vs[m] = fmaf(xv, iM[m], vs[m]);
        }
        #pragma unroll
        for (int i = 0; i < 16; ++i) {
            const int m = i + 1;
            const float xd = half ? X[m + 3] : X[m - 1];
            acc[i] = fmaf(xd * iM[m], vs[m - 1] + vs[m] + vs[m + 1], acc[i]);
        }
        if (chunk == 0) __syncthreads();   // slab consumed before restage
    }

    // ---- channel reduction -> simv ----
    #pragma unroll
    for (int i = 0; i < 16; ++i) acc[i] += __shfl_xor(acc[i], 32);
    float* R = Tarea;                       // [32][8][16], quad-swizzled
    if ((tid & 32) == 0) {
        const int c32 = cS;                 // 0..31
        #pragma unroll
        for (int j = 0; j < 4; ++j)
            *(float4*)&R[c32 * 128 + wv * 16 + ((j ^ (c32 & 3)) << 2)] =
                make_float4(acc[j * 4], acc[j * 4 + 1], acc[j * 4 + 2], acc[j * 4 + 3]);
    }
    __syncthreads();
    {
        const int pos = tid >> 2, g = tid & 3;
        const int s = pos >> 4, ii = pos & 15;
        float sum = 0.f;
        #pragma unroll
        for (int k = 0; k < 8; ++k) {
            const int c32 = g * 8 + k;
            sum += R[c32 * 128 + s * 16 + (((ii >> 2) ^ (c32 & 3)) << 2) + (ii & 3)];
        }
        sum += __shfl_xor(sum, 1);
        sum += __shfl_xor(sum, 2);
        if (g == 0) simv[pos] = sum * (1.0f / 9.0f);
    }
    __syncthreads();

    // ---- phase 3: output transpose ----
    const int p3c  = tid >> 3;              // 0..63
    const int p3wq = tid & 7;
    float4 c3 = *(const float4*)(pb + p3c * 1024 + r0 * 32 + p3wq * 4);
    for (int h = 0; h < 4; ++h) {
        // stage c<64 (from prefetched regs) and c>=64 (from slab, still live)
        *(float4*)&Tarea[(p3c * 9 + (p3wq ^ ((p3c >> 3) & 7))) * 4] = c3;
        {
            const int c = 64 + p3c;
            const float4 v = *(const float4*)&slab[(p3c * 48 + (h + 1) * 8 + (p3wq ^ (p3c & 7))) * 4];
            *(float4*)&Tarea[(c * 9 + (p3wq ^ ((c >> 3) & 7))) * 4] = v;
        }
        __syncthreads();
        if (h < 3) c3 = *(const float4*)(pb + p3c * 1024 + (r0 + h + 1) * 32 + p3wq * 4);
        #pragma unroll
        for (int k2 = 0; k2 < 2; ++k2) {
            const int flat = k2 * 512 + tid;
            const int q4 = flat & 15, w = (flat >> 4) & 31, t = flat >> 9;
            const float sm = simv[(2 * h + (w >> 4)) * 16 + (w & 15)];
            float o[4];
            #pragma unroll
            for (int j = 0; j < 4; ++j) {
                const int c = 8 * q4 + 2 * j + t;
                o[j] = Tarea[c * 36 + (((w >> 2) ^ (q4 & 7)) << 2) + (w & 3)] * sm;
            }
            *(float4*)(out + (size_t)b * 131072 + (size_t)t * 65536 +
                       (size_t)(r0 + h) * 2048 + w * 64 + q4 * 4) =
                make_float4(o[0], o[1], o[2], o[3]);
        }
        __syncthreads();
    }
}

extern "C" void kernel_launch(void* const* d_in, const int* in_sizes, int n_in,
                              void* d_out, int out_size, void* d_ws, size_t ws_size,
                              hipStream_t stream) {
    const float* p = (const float*)d_in[0];
    float* out = (float*)d_out;
    float* inv = (float*)d_ws;   // 256*32*32*4 = 1 MB
    bcim_norm<<<dim3(2048), dim3(NTHR_A), 0, stream>>>(p, inv);
    bcim_main<<<dim3(2048), dim3(NTHR_B), 0, stream>>>(p, inv, out);
    (void)in_sizes; (void)n_in; (void)out_size; (void)ws_size;
}

// Round 6
// 185.682 us; speedup vs baseline: 1.5522x; 1.5522x over previous
//
#include <hip/hip_runtime.h>

// Kernel A: inv[b][h][w] = 1/||p[b,:,h,w]|| via coalesced streaming.
// Kernel B: per (b, 4-row strip):
//   stage q = p*inv in XOR-swizzled LDS slab (4 chunks of 32 channels),
//   thread = (channel, w-quad) computes separable 3x3 box sums for 4h x 4w,
//   acc reduce over channels -> sim, then v3's verified output-transpose tile.
// out[b, c&1, h, w, c>>1] = p[b,c,h,w] * sim[b,h,w]

#define NTHR_A 256
#define NTHR_B 256

__global__ __launch_bounds__(NTHR_A) void bcim_norm(const float* __restrict__ p,
                                                    float* __restrict__ inv) {
    __shared__ float scratch[8 * 4 * 32];
    const int tid = threadIdx.x;
    const int b  = blockIdx.x >> 3;
    const int r0 = (blockIdx.x & 7) << 2;
    const float* __restrict__ pb = p + (size_t)b * 131072;
    const int csub = tid >> 5, r = (tid >> 3) & 3, wq = tid & 7;
    float4 n = make_float4(0.f, 0.f, 0.f, 0.f);
    #pragma unroll
    for (int i = 0; i < 16; ++i) {
        const int c = csub * 16 + i;
        const float4 v = *(const float4*)(pb + c * 1024 + (r0 + r) * 32 + wq * 4);
        n.x = fmaf(v.x, v.x, n.x); n.y = fmaf(v.y, v.y, n.y);
        n.z = fmaf(v.z, v.z, n.z); n.w = fmaf(v.w, v.w, n.w);
    }
    *(float4*)&scratch[csub * 128 + r * 32 + wq * 4] = n;
    __syncthreads();
    if (tid < 128) {
        const int rr = tid >> 5, w = tid & 31;
        float s = 0.f;
        #pragma unroll
        for (int k = 0; k < 8; ++k) s += scratch[k * 128 + rr * 32 + w];
        inv[b * 1024 + (r0 + rr) * 32 + w] = (s > 0.f) ? (1.0f / sqrtf(s)) : 0.f;
    }
}

__global__ __launch_bounds__(NTHR_B, 4) void bcim_main(const float* __restrict__ p,
                                                       const float* __restrict__ inv,
                                                       float* __restrict__ out) {
    __shared__ float slab[6144];   // 1536 quads: [c 0..31][row 0..5][wq^(c&7)]; reused as R and tile
    __shared__ float invL[192];    // rows r0-1..r0+4, OOB rows = 0
    __shared__ float simv[128];

    const int tid = threadIdx.x;
    const int b  = blockIdx.x >> 3;
    const int r0 = (blockIdx.x & 7) << 2;
    const float* __restrict__ pb = p + (size_t)b * 131072;

    const int c32 = tid >> 3;          // 0..31 channel-in-chunk
    const int wq  = tid & 7;           // w-quad
    const int sw  = c32 & 7;
    const float maskL = (wq == 0) ? 0.f : 1.f;
    const float maskR = (wq == 7) ? 0.f : 1.f;
    const int wqmL = ((wq == 0) ? 0 : wq - 1) ^ sw;
    const int wqC  = wq ^ sw;
    const int wqmR = ((wq == 7) ? 7 : wq + 1) ^ sw;

    // global offsets for the 6 staged rows (clamped; inv row=0 nullifies OOB)
    int gOffR[6];
    #pragma unroll
    for (int r = 0; r < 6; ++r) {
        const int rg = min(max(r0 - 1 + r, 0), 31);
        gOffR[r] = c32 * 1024 + rg * 32 + wq * 4;
    }

    // issue chunk-0 loads (independent of invL)
    float4 st[6];
    #pragma unroll
    for (int r = 0; r < 6; ++r) st[r] = *(const float4*)(pb + gOffR[r]);

    // stage invL
    if (tid < 192) {
        const int j = tid >> 5, w = tid & 31;
        const int rg = r0 - 1 + j;
        invL[j * 32 + w] = ((unsigned)rg < 32u) ? inv[b * 1024 + rg * 32 + w] : 0.f;
    }
    __syncthreads();

    // per-thread inv quads (w columns 4wq..4wq+3, 6 rows)
    float4 invq[6];
    #pragma unroll
    for (int r = 0; r < 6; ++r) invq[r] = *(const float4*)&invL[r * 32 + wq * 4];

    float4 acc[4];
    #pragma unroll
    for (int h = 0; h < 4; ++h) acc[h] = make_float4(0.f, 0.f, 0.f, 0.f);

    // phase-3 prefetch regs
    float4 q0, q1, q2, q3;
    const int wq3 = tid & 7;
    const int r3  = (tid >> 3) & 3;
    const int clb = tid >> 5;
    const int p3g = clb * 1024 + (r0 + r3) * 32 + wq3 * 4;

    for (int chunk = 0; chunk < 4; ++chunk) {
        // stage q = p * inv into swizzled slab (b128 writes)
        #pragma unroll
        for (int r = 0; r < 6; ++r) {
            float4 v = st[r];
            v.x *= invq[r].x; v.y *= invq[r].y; v.z *= invq[r].z; v.w *= invq[r].w;
            *(float4*)&slab[(c32 * 48 + r * 8 + wqC) * 4] = v;
        }
        __syncthreads();
        if (chunk < 3) {                       // prefetch next chunk (latency under stencil)
            const int cOff = (chunk + 1) << 15;
            #pragma unroll
            for (int r = 0; r < 6; ++r) st[r] = *(const float4*)(pb + cOff + gOffR[r]);
        } else {                               // prefetch phase-3 cb0 (latency under reduce)
            const float* base = pb + p3g;
            q0 = *(const float4*)(base);
            q1 = *(const float4*)(base + 8192);
            q2 = *(const float4*)(base + 16384);
            q3 = *(const float4*)(base + 24576);
        }
        // separable stencil: hsums per row, then vertical sum + fma
        float hs[6][4];
        float4 ctr[4];
        #pragma unroll
        for (int r = 0; r < 6; ++r) {
            const int qb_ = c32 * 48 + r * 8;
            const float4 L  = *(const float4*)&slab[(qb_ + wqmL) * 4];
            const float4 C  = *(const float4*)&slab[(qb_ + wqC ) * 4];
            const float4 Rr = *(const float4*)&slab[(qb_ + wqmR) * 4];
            if (r >= 1 && r <= 4) ctr[r - 1] = C;
            const float Lw = L.w * maskL;
            const float Rx = Rr.x * maskR;
            hs[r][0] = Lw  + C.x + C.y;
            hs[r][1] = C.x + C.y + C.z;
            hs[r][2] = C.y + C.z + C.w;
            hs[r][3] = C.z + C.w + Rx;
        }
        #pragma unroll
        for (int h = 0; h < 4; ++h) {
            acc[h].x = fmaf(ctr[h].x, hs[h][0] + hs[h+1][0] + hs[h+2][0], acc[h].x);
            acc[h].y = fmaf(ctr[h].y, hs[h][1] + hs[h+1][1] + hs[h+2][1], acc[h].y);
            acc[h].z = fmaf(ctr[h].z, hs[h][2] + hs[h+1][2] + hs[h+2][2], acc[h].z);
            acc[h].w = fmaf(ctr[h].w, hs[h][3] + hs[h+1][3] + hs[h+2][3], acc[h].w);
        }
        __syncthreads();
    }

    // ---- channel reduction: acc -> R (reuse slab) -> simv ----
    #pragma unroll
    for (int h = 0; h < 4; ++h)
        *(float4*)&slab[(c32 * 32 + h * 8 + wqC) * 4] = acc[h];
    __syncthreads();
    if (tid < 128) {
        const int h = tid >> 5, w = tid & 31;
        float s = 0.f;
        #pragma unroll
        for (int c = 0; c < 32; ++c)
            s += slab[(c * 32 + h * 8 + ((w >> 2) ^ (c & 7))) * 4 + (w & 3)];
        simv[tid] = s * (1.0f / 9.0f);
    }
    __syncthreads();

    // ---- phase 3: output transpose via [128 pos][33] rotation tile (v3-verified) ----
    float* T = slab;
    #pragma unroll
    for (int cb = 0; cb < 4; ++cb) {
        {
            int cl, cpp, basew;
            cl = clb;
            cpp = (((cl & 1) << 4) + (cl >> 1) + 9 * r3) & 31;
            basew = (r3 * 32 + wq3 * 4) * 33 + cpp;
            T[basew] = q0.x; T[basew+33] = q0.y; T[basew+66] = q0.z; T[basew+99] = q0.w;
            cl = 8 + clb;
            cpp = (((cl & 1) << 4) + (cl >> 1) + 9 * r3) & 31;
            basew = (r3 * 32 + wq3 * 4) * 33 + cpp;
            T[basew] = q1.x; T[basew+33] = q1.y; T[basew+66] = q1.z; T[basew+99] = q1.w;
            cl = 16 + clb;
            cpp = (((cl & 1) << 4) + (cl >> 1) + 9 * r3) & 31;
            basew = (r3 * 32 + wq3 * 4) * 33 + cpp;
            T[basew] = q2.x; T[basew+33] = q2.y; T[basew+66] = q2.z; T[basew+99] = q2.w;
            cl = 24 + clb;
            cpp = (((cl & 1) << 4) + (cl >> 1) + 9 * r3) & 31;
            basew = (r3 * 32 + wq3 * 4) * 33 + cpp;
            T[basew] = q3.x; T[basew+33] = q3.y; T[basew+66] = q3.z; T[basew+99] = q3.w;
        }
        __syncthreads();
        if (cb < 3) {                          // prefetch next cb (latency under tile reads)
            const float* base = pb + ((cb + 1) << 15) + p3g;
            q0 = *(const float4*)(base);
            q1 = *(const float4*)(base + 8192);
            q2 = *(const float4*)(base + 16384);
            q3 = *(const float4*)(base + 24576);
        }
        const int qb = cb << 4;
        #pragma unroll
        for (int stp = 0; stp < 4; ++stp) {
            const int flat = stp * 256 + tid;
            const int qf = flat & 3;
            const int t  = (flat >> 2) & 1;
            const int pp = flat >> 3;
            const int hh = pp >> 5;
            const int ww = pp & 31;
            const float sm = simv[pp];
            const int cb2 = t * 16 + qf * 4 + 9 * hh;
            const int ai  = pp * 33;
            float4 o;
            o.x = T[ai + ((cb2 + 0) & 31)] * sm;
            o.y = T[ai + ((cb2 + 1) & 31)] * sm;
            o.z = T[ai + ((cb2 + 2) & 31)] * sm;
            o.w = T[ai + ((cb2 + 3) & 31)] * sm;
            *(float4*)(out + (size_t)b * 131072 + (size_t)t * 65536 +
                       (size_t)(r0 + hh) * 2048 + ww * 64 + qb + qf * 4) = o;
        }
        __syncthreads();
    }
}

extern "C" void kernel_launch(void* const* d_in, const int* in_sizes, int n_in,
                              void* d_out, int out_size, void* d_ws, size_t ws_size,
                              hipStream_t stream) {
    const float* p = (const float*)d_in[0];
    float* out = (float*)d_out;
    float* inv = (float*)d_ws;   // 1 MB
    bcim_norm<<<dim3(2048), dim3(NTHR_A), 0, stream>>>(p, inv);
    bcim_main<<<dim3(2048), dim3(NTHR_B), 0, stream>>>(p, inv, out);
    (void)in_sizes; (void)n_in; (void)out_size; (void)ws_size;
}

// Round 7
// 103.493 us; speedup vs baseline: 2.7849x; 1.7941x over previous
//
#include <hip/hip_runtime.h>

// Kernel A: inv[b][h][w] = 1/||p[b,:,h,w]|| (coalesced cold read of p).
// Kernel B: per (b, 4-row strip). Stencil reads p DIRECTLY from global (L3-warm
// after A) — no LDS slab, no register staging arrays. Thread (c32, wq) owns a
// 4-wide w segment for channels {c32, c32+32, c32+64, c32+96}; per row loads
// center float4 + 2 edge scalars, q = p*inv (inv from LDS), separable 3x3 box,
// one accumulator float4[4]. Reduce over channels via swizzled LDS, then v6's
// verified output-transpose tile.
// out[b, c&1, h, w, c>>1] = p[b,c,h,w] * sim[b,h,w]

#define NTHR_A 256
#define NTHR_B 256

__global__ __launch_bounds__(NTHR_A) void bcim_norm(const float* __restrict__ p,
                                                    float* __restrict__ inv) {
    __shared__ float scratch[8 * 4 * 32];
    const int tid = threadIdx.x;
    const int b  = blockIdx.x >> 3;
    const int r0 = (blockIdx.x & 7) << 2;
    const float* __restrict__ pb = p + (size_t)b * 131072;
    const int csub = tid >> 5, r = (tid >> 3) & 3, wq = tid & 7;
    float4 n = make_float4(0.f, 0.f, 0.f, 0.f);
    #pragma unroll
    for (int i = 0; i < 16; ++i) {
        const int c = csub * 16 + i;
        const float4 v = *(const float4*)(pb + c * 1024 + (r0 + r) * 32 + wq * 4);
        n.x = fmaf(v.x, v.x, n.x); n.y = fmaf(v.y, v.y, n.y);
        n.z = fmaf(v.z, v.z, n.z); n.w = fmaf(v.w, v.w, n.w);
    }
    *(float4*)&scratch[csub * 128 + r * 32 + wq * 4] = n;
    __syncthreads();
    if (tid < 128) {
        const int rr = tid >> 5, w = tid & 31;
        float s = 0.f;
        #pragma unroll
        for (int k = 0; k < 8; ++k) s += scratch[k * 128 + rr * 32 + w];
        inv[b * 1024 + (rr + r0) * 32 + w] = (s > 0.f) ? (1.0f / sqrtf(s)) : 0.f;
    }
}

__global__ __launch_bounds__(NTHR_B) void bcim_main(const float* __restrict__ p,
                                                    const float* __restrict__ inv,
                                                    float* __restrict__ out) {
    __shared__ float T[4224];      // reduce slab R[32][4][8]*4 (4096 f) / transpose tile [128][33]
    __shared__ float invL[192];    // rows r0-1..r0+4, 0 for OOB rows
    __shared__ float simv[128];

    const int tid = threadIdx.x;
    const int b  = blockIdx.x >> 3;
    const int r0 = (blockIdx.x & 7) << 2;
    const float* __restrict__ pb = p + (size_t)b * 131072;

    const int c32 = tid >> 3;      // 0..31
    const int wq  = tid & 7;       // w-quad

    if (tid < 192) {
        const int j = tid >> 5, w = tid & 31;
        const int rg = r0 - 1 + j;
        invL[j * 32 + w] = ((unsigned)rg < 32u) ? inv[b * 1024 + rg * 32 + w] : 0.f;
    }
    __syncthreads();

    // clamped row offsets (OOB rows nullified by invL = 0)
    int rOff[6];
    #pragma unroll
    for (int r = 0; r < 6; ++r) rOff[r] = min(max(r0 - 1 + r, 0), 31) * 32;

    float4 acc[4];
    #pragma unroll
    for (int h = 0; h < 4; ++h) acc[h] = make_float4(0.f, 0.f, 0.f, 0.f);

    for (int chunk = 0; chunk < 4; ++chunk) {
        const float* base = pb + ((chunk << 5) + c32) * 1024 + wq * 4;
        float vs[6][4];
        float4 ctr[4];
        #pragma unroll
        for (int r = 0; r < 6; ++r) {
            const float* rowp = base + rOff[r];
            const float4 P = *(const float4*)rowp;
            const float pl = (wq > 0) ? rowp[-1] : 0.f;
            const float pr = (wq < 7) ? rowp[4]  : 0.f;
            const float4 IV = *(const float4*)&invL[r * 32 + wq * 4];
            const float il = (wq > 0) ? invL[r * 32 + wq * 4 - 1] : 0.f;
            const float ir = (wq < 7) ? invL[r * 32 + wq * 4 + 4] : 0.f;
            float4 q;
            q.x = P.x * IV.x; q.y = P.y * IV.y; q.z = P.z * IV.z; q.w = P.w * IV.w;
            const float ql = pl * il;
            const float qr = pr * ir;
            vs[r][0] = ql  + q.x + q.y;
            vs[r][1] = q.x + q.y + q.z;
            vs[r][2] = q.y + q.z + q.w;
            vs[r][3] = q.z + q.w + qr;
            if (r >= 1 && r <= 4) ctr[r - 1] = q;
        }
        #pragma unroll
        for (int h = 0; h < 4; ++h) {
            acc[h].x = fmaf(ctr[h].x, vs[h][0] + vs[h+1][0] + vs[h+2][0], acc[h].x);
            acc[h].y = fmaf(ctr[h].y, vs[h][1] + vs[h+1][1] + vs[h+2][1], acc[h].y);
            acc[h].z = fmaf(ctr[h].z, vs[h][2] + vs[h+1][2] + vs[h+2][2], acc[h].z);
            acc[h].w = fmaf(ctr[h].w, vs[h][3] + vs[h+1][3] + vs[h+2][3], acc[h].w);
        }
    }

    // ---- phase-3 cb0 prefetch (latency hides under reduce) ----
    const int wq3 = tid & 7;
    const int r3  = (tid >> 3) & 3;
    const int clb = tid >> 5;
    const int p3g = clb * 1024 + (r0 + r3) * 32 + wq3 * 4;
    float4 q0 = *(const float4*)(pb + p3g);
    float4 q1 = *(const float4*)(pb + p3g + 8192);
    float4 q2 = *(const float4*)(pb + p3g + 16384);
    float4 q3 = *(const float4*)(pb + p3g + 24576);

    // ---- channel reduction -> simv ----
    const int wqC = wq ^ (c32 & 7);
    #pragma unroll
    for (int h = 0; h < 4; ++h)
        *(float4*)&T[(c32 * 32 + h * 8 + wqC) * 4] = acc[h];
    __syncthreads();
    if (tid < 128) {
        const int h = tid >> 5, w = tid & 31;
        float s = 0.f;
        #pragma unroll
        for (int c = 0; c < 32; ++c)
            s += T[(c * 32 + h * 8 + ((w >> 2) ^ (c & 7))) * 4 + (w & 3)];
        simv[tid] = s * (1.0f / 9.0f);
    }
    __syncthreads();

    // ---- phase 3: output transpose via [128 pos][33] rotation tile (verified) ----
    #pragma unroll
    for (int cb = 0; cb < 4; ++cb) {
        {
            int cl, cpp, basew;
            cl = clb;
            cpp = (((cl & 1) << 4) + (cl >> 1) + 9 * r3) & 31;
            basew = (r3 * 32 + wq3 * 4) * 33 + cpp;
            T[basew] = q0.x; T[basew+33] = q0.y; T[basew+66] = q0.z; T[basew+99] = q0.w;
            cl = 8 + clb;
            cpp = (((cl & 1) << 4) + (cl >> 1) + 9 * r3) & 31;
            basew = (r3 * 32 + wq3 * 4) * 33 + cpp;
            T[basew] = q1.x; T[basew+33] = q1.y; T[basew+66] = q1.z; T[basew+99] = q1.w;
            cl = 16 + clb;
            cpp = (((cl & 1) << 4) + (cl >> 1) + 9 * r3) & 31;
            basew = (r3 * 32 + wq3 * 4) * 33 + cpp;
            T[basew] = q2.x; T[basew+33] = q2.y; T[basew+66] = q2.z; T[basew+99] = q2.w;
            cl = 24 + clb;
            cpp = (((cl & 1) << 4) + (cl >> 1) + 9 * r3) & 31;
            basew = (r3 * 32 + wq3 * 4) * 33 + cpp;
            T[basew] = q3.x; T[basew+33] = q3.y; T[basew+66] = q3.z; T[basew+99] = q3.w;
        }
        __syncthreads();
        if (cb < 3) {   // prefetch next cb (latency hides under tile reads)
            const float* nb = pb + ((cb + 1) << 15) + p3g;
            q0 = *(const float4*)(nb);
            q1 = *(const float4*)(nb + 8192);
            q2 = *(const float4*)(nb + 16384);
            q3 = *(const float4*)(nb + 24576);
        }
        const int qb = cb << 4;
        #pragma unroll
        for (int stp = 0; stp < 4; ++stp) {
            const int flat = stp * 256 + tid;
            const int qf = flat & 3;
            const int t  = (flat >> 2) & 1;
            const int pp = flat >> 3;
            const int hh = pp >> 5;
            const int ww = pp & 31;
            const float sm = simv[pp];
            const int cb2 = t * 16 + qf * 4 + 9 * hh;
            const int ai  = pp * 33;
            float4 o;
            o.x = T[ai + ((cb2 + 0) & 31)] * sm;
            o.y = T[ai + ((cb2 + 1) & 31)] * sm;
            o.z = T[ai + ((cb2 + 2) & 31)] * sm;
            o.w = T[ai + ((cb2 + 3) & 31)] * sm;
            *(float4*)(out + (size_t)b * 131072 + (size_t)t * 65536 +
                       (size_t)(r0 + hh) * 2048 + ww * 64 + qb + qf * 4) = o;
        }
        __syncthreads();
    }
}

extern "C" void kernel_launch(void* const* d_in, const int* in_sizes, int n_in,
                              void* d_out, int out_size, void* d_ws, size_t ws_size,
                              hipStream_t stream) {
    const float* p = (const float*)d_in[0];
    float* out = (float*)d_out;
    float* inv = (float*)d_ws;   // 1 MB
    bcim_norm<<<dim3(2048), dim3(NTHR_A), 0, stream>>>(p, inv);
    bcim_main<<<dim3(2048), dim3(NTHR_B), 0, stream>>>(p, inv, out);
    (void)in_sizes; (void)n_in; (void)out_size; (void)ws_size;
}